// Round 1
// baseline (87.334 us; speedup 1.0000x reference)
//
#include <hip/hip_runtime.h>
#include <math.h>

#define NROWS 2048
#define INF_ 512
#define OUTF 256

// Partial max/min over a K-slice for a 64x64 output tile.
// 256 threads, thread = (tx:j-group 0..15, ty:n-group 0..15), 4x4 register tile.
__global__ __launch_bounds__(256) void mam_partial(
    const float* __restrict__ x, const float* __restrict__ w,
    float* __restrict__ pmax, float* __restrict__ pmin, int kLen)
{
    // +4 pad keeps 16B alignment for float4 LDS reads (row stride 272 B) and
    // spreads transpose-write bank pattern (~4-way worst case, staging only).
    __shared__ __align__(16) float xs[32][68];
    __shared__ __align__(16) float wsh[32][68];

    const int t  = threadIdx.x;
    const int j0 = blockIdx.x * 64;
    const int n0 = blockIdx.y * 64;
    const int k0 = blockIdx.z * kLen;

    const int tx = t & 15;   // j group
    const int ty = t >> 4;   // n group

    float mx[4][4], mn[4][4];
#pragma unroll
    for (int i = 0; i < 4; ++i)
#pragma unroll
        for (int j = 0; j < 4; ++j) {
            mx[i][j] = -__builtin_inff();
            mn[i][j] =  __builtin_inff();
        }

    for (int c = 0; c < kLen; c += 32) {
        const int kc = k0 + c;
        // Stage x tile: rows n0..n0+63, k kc..kc+31  (2048 floats, 2 float4/thread)
#pragma unroll
        for (int p = 0; p < 2; ++p) {
            int idx = t + p * 256;
            int n = idx >> 3, kv = idx & 7;
            float4 g = ((const float4*)(x + (size_t)(n0 + n) * INF_ + kc))[kv];
            xs[kv * 4 + 0][n] = g.x;
            xs[kv * 4 + 1][n] = g.y;
            xs[kv * 4 + 2][n] = g.z;
            xs[kv * 4 + 3][n] = g.w;
        }
        // Stage w tile: weight rows j0..j0+63 (output cols), same ks
#pragma unroll
        for (int p = 0; p < 2; ++p) {
            int idx = t + p * 256;
            int j = idx >> 3, kv = idx & 7;
            float4 g = ((const float4*)(w + (size_t)(j0 + j) * INF_ + kc))[kv];
            wsh[kv * 4 + 0][j] = g.x;
            wsh[kv * 4 + 1][j] = g.y;
            wsh[kv * 4 + 2][j] = g.z;
            wsh[kv * 4 + 3][j] = g.w;
        }
        __syncthreads();

#pragma unroll
        for (int kk = 0; kk < 32; ++kk) {
            float4 xv = *(const float4*)&xs[kk][ty * 4];
            float4 wv = *(const float4*)&wsh[kk][tx * 4];
            float xa[4] = {xv.x, xv.y, xv.z, xv.w};
            float wa[4] = {wv.x, wv.y, wv.z, wv.w};
#pragma unroll
            for (int i = 0; i < 4; ++i)
#pragma unroll
                for (int j = 0; j < 4; ++j) {
                    float p = xa[i] * wa[j];
                    mx[i][j] = fmaxf(mx[i][j], p);
                    mn[i][j] = fminf(mn[i][j], p);
                }
        }
        __syncthreads();
    }

    // Store partials: pmax/pmin[s][n][j]
    const size_t sOff = (size_t)blockIdx.z * NROWS * OUTF;
#pragma unroll
    for (int i = 0; i < 4; ++i) {
        size_t row = (size_t)(n0 + ty * 4 + i) * OUTF + j0 + tx * 4;
        float4 vmx = make_float4(mx[i][0], mx[i][1], mx[i][2], mx[i][3]);
        float4 vmn = make_float4(mn[i][0], mn[i][1], mn[i][2], mn[i][3]);
        *(float4*)(pmax + sOff + row) = vmx;
        *(float4*)(pmin + sOff + row) = vmn;
    }
}

// Fold K-splits, add bias. One float4 per thread over 2048x256 outputs.
__global__ __launch_bounds__(256) void mam_combine(
    const float* __restrict__ pmax, const float* __restrict__ pmin,
    const float* __restrict__ bias, float* __restrict__ out, int S)
{
    const int f = blockIdx.x * 256 + threadIdx.x;  // float4 index, 131072 total
    const int PLANE4 = NROWS * OUTF / 4;
    const float4* pm4 = (const float4*)pmax;
    const float4* pn4 = (const float4*)pmin;

    float4 a = pm4[f];
    float4 b = pn4[f];
    for (int s = 1; s < S; ++s) {
        float4 a2 = pm4[(size_t)s * PLANE4 + f];
        float4 b2 = pn4[(size_t)s * PLANE4 + f];
        a.x = fmaxf(a.x, a2.x); a.y = fmaxf(a.y, a2.y);
        a.z = fmaxf(a.z, a2.z); a.w = fmaxf(a.w, a2.w);
        b.x = fminf(b.x, b2.x); b.y = fminf(b.y, b2.y);
        b.z = fminf(b.z, b2.z); b.w = fminf(b.w, b2.w);
    }
    float4 bi = ((const float4*)bias)[f & 63];  // 64 float4 per output row
    float4 o;
    o.x = a.x + b.x + bi.x;
    o.y = a.y + b.y + bi.y;
    o.z = a.z + b.z + bi.z;
    o.w = a.w + b.w + bi.w;
    ((float4*)out)[f] = o;
}

// Correct-but-slow fallback if d_ws is too small for partials.
__global__ __launch_bounds__(256) void mam_naive(
    const float* __restrict__ x, const float* __restrict__ w,
    const float* __restrict__ bias, float* __restrict__ out)
{
    const int n = blockIdx.x;
    const int j = threadIdx.x;
    float mx = -__builtin_inff(), mn = __builtin_inff();
    for (int k = 0; k < INF_; ++k) {
        float p = x[(size_t)n * INF_ + k] * w[(size_t)j * INF_ + k];
        mx = fmaxf(mx, p);
        mn = fminf(mn, p);
    }
    out[(size_t)n * OUTF + j] = mx + mn + bias[j];
}

extern "C" void kernel_launch(void* const* d_in, const int* in_sizes, int n_in,
                              void* d_out, int out_size, void* d_ws, size_t ws_size,
                              hipStream_t stream) {
    const float* x    = (const float*)d_in[0];
    const float* w    = (const float*)d_in[1];
    const float* bias = (const float*)d_in[2];
    float* out = (float*)d_out;

    const size_t plane = (size_t)NROWS * OUTF * sizeof(float);  // 2 MB
    int S;
    if      (ws_size >= 8 * plane) S = 4;   // 512 blocks, 2/CU
    else if (ws_size >= 4 * plane) S = 2;   // 256 blocks, 1/CU
    else if (ws_size >= 2 * plane) S = 1;   // 128 blocks (half GPU idle)
    else                           S = 0;   // no workspace: naive path

    if (S > 0) {
        float* pmax = (float*)d_ws;
        float* pmin = pmax + (size_t)S * NROWS * OUTF;
        dim3 grid(OUTF / 64, NROWS / 64, S);
        mam_partial<<<grid, 256, 0, stream>>>(x, w, pmax, pmin, INF_ / S);
        mam_combine<<<(NROWS * OUTF / 4) / 256, 256, 0, stream>>>(pmax, pmin, bias, out, S);
    } else {
        mam_naive<<<NROWS, 256, 0, stream>>>(x, w, bias, out);
    }
}

// Round 2
// 82.941 us; speedup vs baseline: 1.0530x; 1.0530x over previous
//
#include <hip/hip_runtime.h>
#include <math.h>

#define N_ 2048
#define K_ 512
#define J_ 256
#define TN 64
#define TJ 32
#define BK 256
#define RP 260   // LDS row pitch (floats): 16B-aligned rows; x-reads 2-way (free), w-reads 4-way

typedef __attribute__((address_space(3))) float       lds_f;
typedef const __attribute__((address_space(1))) float glb_f;

// One fused kernel, no workspace. Grid 256 blocks (1/CU), 256 threads.
// Per block: 64(n) x 32(j) output tile, K=512 in 2 chunks of 256.
// Per thread: 4(n) x 2(j) register tile, k vectorized x4 via ds_read_b128.
__global__ __launch_bounds__(256) void mam_fused(
    const float* __restrict__ x, const float* __restrict__ w,
    const float* __restrict__ bias, float* __restrict__ out)
{
    __shared__ __align__(16) float xs[TN * RP];   // 66,560 B
    __shared__ __align__(16) float wsh[TJ * RP];  // 33,280 B

    const int t    = threadIdx.x;
    const int lane = t & 63;
    const int wid  = t >> 6;          // wave 0..3
    const int j0   = blockIdx.x * TJ;
    const int n0   = blockIdx.y * TN;
    const int tx   = t & 15;          // j group (2 cols each)
    const int ty   = t >> 4;          // n group (4 rows each)

    float mx[4][2], mn[4][2];
#pragma unroll
    for (int i = 0; i < 4; ++i)
#pragma unroll
        for (int j = 0; j < 2; ++j) {
            mx[i][j] = -__builtin_inff();
            mn[i][j] =  __builtin_inff();
        }

    for (int kc = 0; kc < K_; kc += BK) {
        // Stage x tile: 64 rows x 256 floats. One global_load_lds(16B) moves a
        // full row per wave (uniform LDS base + lane*16). Wave w: rows 16w..16w+15.
#pragma unroll
        for (int r = 0; r < 16; ++r) {
            const int row = wid * 16 + r;
            __builtin_amdgcn_global_load_lds(
                (glb_f*)(x + (size_t)(n0 + row) * K_ + kc + lane * 4),
                (lds_f*)(xs + row * RP), 16, 0, 0);
        }
        // Stage w tile: 32 rows. Wave w: rows 8w..8w+7.
#pragma unroll
        for (int r = 0; r < 8; ++r) {
            const int row = wid * 8 + r;
            __builtin_amdgcn_global_load_lds(
                (glb_f*)(w + (size_t)(j0 + row) * K_ + kc + lane * 4),
                (lds_f*)(wsh + row * RP), 16, 0, 0);
        }
        __syncthreads();   // compiler emits vmcnt(0) drain before s_barrier

#pragma unroll 4
        for (int kk = 0; kk < BK; kk += 4) {
            float4 xv[4], wq[2];
#pragma unroll
            for (int i = 0; i < 4; ++i)
                xv[i] = *(const float4*)&xs[(ty * 4 + i) * RP + kk];
#pragma unroll
            for (int j = 0; j < 2; ++j)
                wq[j] = *(const float4*)&wsh[(tx * 2 + j) * RP + kk];
#pragma unroll
            for (int i = 0; i < 4; ++i) {
                const float xa[4] = {xv[i].x, xv[i].y, xv[i].z, xv[i].w};
#pragma unroll
                for (int j = 0; j < 2; ++j) {
                    const float wa[4] = {wq[j].x, wq[j].y, wq[j].z, wq[j].w};
#pragma unroll
                    for (int q = 0; q < 4; ++q) {
                        const float p = xa[q] * wa[q];
                        mx[i][j] = fmaxf(mx[i][j], p);
                        mn[i][j] = fminf(mn[i][j], p);
                    }
                }
            }
        }
        __syncthreads();
    }

    const float2 bi = *(const float2*)&bias[j0 + tx * 2];
#pragma unroll
    for (int i = 0; i < 4; ++i) {
        float2 o;
        o.x = mx[i][0] + mn[i][0] + bi.x;
        o.y = mx[i][1] + mn[i][1] + bi.y;
        *(float2*)&out[(size_t)(n0 + ty * 4 + i) * J_ + j0 + tx * 2] = o;
    }
}

extern "C" void kernel_launch(void* const* d_in, const int* in_sizes, int n_in,
                              void* d_out, int out_size, void* d_ws, size_t ws_size,
                              hipStream_t stream) {
    const float* x    = (const float*)d_in[0];
    const float* w    = (const float*)d_in[1];
    const float* bias = (const float*)d_in[2];
    float* out = (float*)d_out;

    dim3 grid(J_ / TJ, N_ / TN);   // 8 x 32 = 256 blocks
    mam_fused<<<grid, 256, 0, stream>>>(x, w, bias, out);
}